// Round 8
// baseline (485.292 us; speedup 1.0000x reference)
//
#include <hip/hip_runtime.h>

// B=128, S=1024, H=256
#define Bb 128
#define Ss 1024
#define Hh 256
#define NEGF 1e9f

typedef short bf16x8 __attribute__((ext_vector_type(8)));
typedef float f32x4 __attribute__((ext_vector_type(4)));

__device__ __forceinline__ short f2bf(float f) {
    union { float f; unsigned u; } c; c.f = f;
    return (short)((c.u + 0x8000u) >> 16);
}

__device__ __forceinline__ float bfhi2f(unsigned u) {
    union { unsigned u; float f; } c; c.u = u & 0xFFFF0000u; return c.f;
}
__device__ __forceinline__ float bflo2f(unsigned u) {
    union { unsigned u; float f; } c; c.u = u << 16; return c.f;
}

// packed fp32->bf16 (RNE), 1 instr per 2 elements
__device__ __forceinline__ unsigned cvt_pk_bf16(float a, float b) {
    unsigned r;
    asm("v_cvt_pk_bf16_f32 %0, %1, %2" : "=v"(r) : "v"(a), "v"(b));
    return r;
}

__device__ __forceinline__ float fast_tanh(float x) {
    float cl = fminf(fmaxf(x, -10.f), 10.f);
    float e = __expf(2.f * cl);
    return (e - 1.f) * __builtin_amdgcn_rcpf(e + 1.f);
}

// ---------------- prep: wg,wp -> bf16 (blocks 0..255); qbias_g (blocks 256..383)
__global__ __launch_bounds__(256) void prep_kernel(const float* __restrict__ wg,
                                                   const float* __restrict__ wp,
                                                   const float* __restrict__ query,
                                                   const float* __restrict__ wqg,
                                                   const float* __restrict__ bg,
                                                   short* __restrict__ wgb,
                                                   short* __restrict__ wpb,
                                                   float* __restrict__ qbias_g) {
    int blk = blockIdx.x, t = threadIdx.x;
    if (blk < 256) {
        int i = blk * 256 + t;
        wgb[i] = f2bf(wg[i]);
        wpb[i] = f2bf(wp[i]);
    } else {
        int b = blk - 256;
        const float4* qr = (const float4*)(query + b * Hh);
        const float4* wr = (const float4*)(wqg + t * Hh);
        float acc = 0.f;
#pragma unroll 8
        for (int i = 0; i < Hh / 4; ++i) {
            float4 q4 = qr[i], w4 = wr[i];
            acc += q4.x * w4.x + q4.y * w4.y + q4.z * w4.z + q4.w * w4.w;
        }
        qbias_g[b * Hh + t] = acc + bg[t];
    }
}

// ---------------- Fused scores GEMM v8: one wave = one 16-row tile, slices in time.
// Grid = 2048 blocks x 256 threads (4 waves); 8192 INDEPENDENT wave-jobs, 8 waves/SIMD
// queued (VGPR ~120 -> 4 resident). NO LDS, NO barriers, NO cross-wave anything:
// every prior version was iteration/latency-bound (VALUBusy<17%, Occ<28%) because
// 8-16 barrier-coupled waves/block propagate every stall; here the scheduler always
// has independent waves to rotate in, and per-slice 16-24 outstanding loads give MLP.
// Per wave: load A tile once (afrag[8], verified mapping k=kb*32+quad*8+j), then for
// slice s=0..7: load W rows [s*32,s*32+32) into bf0/bf1 (L2-hot, 128 KB total W;
// aggregate re-read 256 MB ~ 7us at L2 BW), 16 MFMA (two 8-chains), accumulate
// rs[r] += tanh(c0+qb)*vv0 + tanh(c1+qb)*vv1. Union over slices x {c0,c1} x nl
// covers all 256 n exactly once -> one final shfl_xor over the 16 n-lanes = full
// reduction (same math as verified r2 structure, slices in time instead of waves).
// Pass 1 (LOADF32): fp32 in, cvt_pk convert, side-write bf16 tile (tile is
// wave-exclusive -> plain stores, no protocol).
template <int MASKED, int LOADF32>
__global__ __launch_bounds__(256) void scores_mfma(const float* __restrict__ reff,
                                                   const short* __restrict__ refb_in,
                                                   short* __restrict__ refb_out,
                                                   const short* __restrict__ Wbf,
                                                   const float* __restrict__ qbias,
                                                   const float* __restrict__ vvec,
                                                   const int* __restrict__ mask,
                                                   float* __restrict__ out) {
    const int T = blockIdx.x * 4 + (threadIdx.x >> 6);  // tile id 0..8191
    const int lane = threadIdx.x & 63;
    const int nl = lane & 15;
    const int quad = lane >> 4;
    const int b = T >> 6;                // 64 tiles per batch
    const int row0 = (T & 63) * 16;
    const size_t abase = ((size_t)b * Ss + row0 + nl) * Hh + quad * 8;  // element idx

    // ---- A fragments (one tile, loaded once) ----
    bf16x8 afrag[8];
    if (LOADF32) {
        float4 f[16];
        const float* rp = reff + abase;
#pragma unroll
        for (int kb = 0; kb < 8; ++kb) {
            f[2 * kb]     = *(const float4*)(rp + kb * 32);
            f[2 * kb + 1] = *(const float4*)(rp + kb * 32 + 4);
        }
#pragma unroll
        for (int kb = 0; kb < 8; ++kb) {
            union { unsigned u[4]; bf16x8 v; } cv;
            cv.u[0] = cvt_pk_bf16(f[2 * kb].x,     f[2 * kb].y);
            cv.u[1] = cvt_pk_bf16(f[2 * kb].z,     f[2 * kb].w);
            cv.u[2] = cvt_pk_bf16(f[2 * kb + 1].x, f[2 * kb + 1].y);
            cv.u[3] = cvt_pk_bf16(f[2 * kb + 1].z, f[2 * kb + 1].w);
            afrag[kb] = cv.v;
            *(bf16x8*)(refb_out + abase + kb * 32) = cv.v;  // bf16 side-output
        }
    } else {
        const short* rp = refb_in + abase;
#pragma unroll
        for (int kb = 0; kb < 8; ++kb)
            afrag[kb] = *(const bf16x8*)(rp + kb * 32);
    }

    const float* qb = qbias + b * Hh;
    float rs[4] = {0.f, 0.f, 0.f, 0.f};

#pragma unroll 1
    for (int s = 0; s < 8; ++s) {
        // W fragments for n-slice s: lane (nl,quad) holds W[s*32+{nl,16+nl}][kb*32+quad*8..+8)
        const short* w0 = Wbf + (s * 32 + nl) * Hh + quad * 8;
        const short* w1 = w0 + 16 * Hh;
        bf16x8 bf0[8], bf1[8];
#pragma unroll
        for (int kb = 0; kb < 8; ++kb) {
            bf0[kb] = *(const bf16x8*)(w0 + kb * 32);
            bf1[kb] = *(const bf16x8*)(w1 + kb * 32);
        }
        f32x4 c0 = {0.f, 0.f, 0.f, 0.f};
        f32x4 c1 = {0.f, 0.f, 0.f, 0.f};
#pragma unroll
        for (int kb = 0; kb < 8; ++kb) {
            c0 = __builtin_amdgcn_mfma_f32_16x16x32_bf16(afrag[kb], bf0[kb], c0, 0, 0, 0);
            c1 = __builtin_amdgcn_mfma_f32_16x16x32_bf16(afrag[kb], bf1[kb], c1, 0, 0, 0);
        }
        const float q0 = qb[s * 32 + nl],       q1 = qb[s * 32 + 16 + nl];
        const float v0 = vvec[s * 32 + nl],     v1 = vvec[s * 32 + 16 + nl];
        // C/D: col = lane&15 (n-lane), row = quad*4 + r
#pragma unroll
        for (int r = 0; r < 4; ++r)
            rs[r] += fast_tanh(c0[r] + q0) * v0 + fast_tanh(c1[r] + q1) * v1;
    }

    // reduce over the 16 n-lanes; rows are wave-exclusive -> direct store
#pragma unroll
    for (int r = 0; r < 4; ++r) {
        float v = rs[r];
        v += __shfl_xor(v, 1, 64);
        v += __shfl_xor(v, 2, 64);
        v += __shfl_xor(v, 4, 64);
        v += __shfl_xor(v, 8, 64);
        if (nl == 0) {
            int m = row0 + quad * 4 + r;
            if (MASKED) v -= (float)mask[b * Ss + m] * NEGF;
            out[(size_t)b * Ss + m] = v;
        }
    }
}

// ---------------- Softmax over S per batch (mask applied) -> att ----------------
__global__ __launch_bounds__(1024) void softmax_kernel(const float* __restrict__ scores,
                                                       const int* __restrict__ mask,
                                                       float* __restrict__ att) {
    int b = blockIdx.x, t = threadIdx.x;
    __shared__ float red[16];
    int idx = b * Ss + t;
    float x = scores[idx] - (float)mask[idx] * NEGF;

    float m = x;
#pragma unroll
    for (int o = 1; o < 64; o <<= 1) m = fmaxf(m, __shfl_xor(m, o, 64));
    if ((t & 63) == 0) red[t >> 6] = m;
    __syncthreads();
    float M = red[0];
#pragma unroll
    for (int j = 1; j < 16; ++j) M = fmaxf(M, red[j]);
    __syncthreads();

    float e = __expf(x - M);
    float s = e;
#pragma unroll
    for (int o = 1; o < 64; o <<= 1) s += __shfl_xor(s, o, 64);
    if ((t & 63) == 0) red[t >> 6] = s;
    __syncthreads();
    float S = 0.f;
#pragma unroll
    for (int j = 0; j < 16; ++j) S += red[j];

    att[idx] = e * __builtin_amdgcn_rcpf(S);
}

// ---------------- Glimpse partial (bf16 ref, L3-hot): gpart[b,q,d] = sum att*ref
__global__ __launch_bounds__(256) void glimpse_part(const unsigned* __restrict__ refb,
                                                    const float* __restrict__ att,
                                                    float* __restrict__ gpart) {
    int b = blockIdx.x, q = blockIdx.y, t = threadIdx.x;
    const int c = t & 31;      // 16B chunk: d = c*8 .. c*8+7
    const int rg = t >> 5;     // row group 0..7
    __shared__ float part[8][Hh];
    const unsigned* base = refb + ((size_t)(b * Ss + q * 128)) * (Hh / 2);
    const float* ap = att + b * Ss + q * 128;

    float acc[8] = {0.f, 0.f, 0.f, 0.f, 0.f, 0.f, 0.f, 0.f};
#pragma unroll 4
    for (int it = 0; it < 16; ++it) {
        int row = it * 8 + rg;
        float a = ap[row];
        uint4 v = *(const uint4*)(base + (size_t)row * (Hh / 2) + c * 4);
        acc[0] += a * bflo2f(v.x); acc[1] += a * bfhi2f(v.x);
        acc[2] += a * bflo2f(v.y); acc[3] += a * bfhi2f(v.y);
        acc[4] += a * bflo2f(v.z); acc[5] += a * bfhi2f(v.z);
        acc[6] += a * bflo2f(v.w); acc[7] += a * bfhi2f(v.w);
    }
#pragma unroll
    for (int j = 0; j < 8; ++j) part[rg][c * 8 + j] = acc[j];
    __syncthreads();
    float s = 0.f;
#pragma unroll
    for (int g = 0; g < 8; ++g) s += part[g][t];
    gpart[(size_t)(b * 8 + q) * Hh + t] = s;
}

// ---------------- qbias_p[b,h] = sum_d glimpse[b,d]*wqp[h,d] + bp[h] ------------
__global__ __launch_bounds__(256) void qbias_p_kernel(const float* __restrict__ gpart,
                                                      const float* __restrict__ query,
                                                      const float* __restrict__ wqp,
                                                      const float* __restrict__ bp,
                                                      float* __restrict__ out) {
    int b = blockIdx.x, t = threadIdx.x;
    __shared__ __align__(16) float gl[Hh];
    float g = query[b * Hh + t];
#pragma unroll
    for (int q = 0; q < 8; ++q) g += gpart[(b * 8 + q) * Hh + t];
    gl[t] = g;
    __syncthreads();
    const float4* wr = (const float4*)(wqp + t * Hh);
    const float4* gp = (const float4*)gl;
    float acc = 0.f;
#pragma unroll 8
    for (int i = 0; i < Hh / 4; ++i) {
        float4 w4 = wr[i];
        float4 g4 = gp[i];
        acc += w4.x * g4.x + w4.y * g4.y + w4.z * g4.z + w4.w * g4.w;
    }
    out[b * Hh + t] = acc + bp[t];
}

extern "C" void kernel_launch(void* const* d_in, const int* in_sizes, int n_in,
                              void* d_out, int out_size, void* d_ws, size_t ws_size,
                              hipStream_t stream) {
    const float* ref   = (const float*)d_in[0];
    const float* query = (const float*)d_in[1];
    const int*   mask  = (const int*)d_in[2];
    const float* wg    = (const float*)d_in[3];
    const float* bg    = (const float*)d_in[4];
    const float* wqg   = (const float*)d_in[5];
    const float* vg    = (const float*)d_in[6];
    const float* wp    = (const float*)d_in[7];
    const float* bp    = (const float*)d_in[8];
    const float* wqp   = (const float*)d_in[9];
    const float* vp    = (const float*)d_in[10];
    float* out = (float*)d_out;

    char* ws = (char*)d_ws;
    short* ref_bf   = (short*)(ws + 0);          // 64 MB (B*S*H bf16)
    size_t off = (size_t)Bb * Ss * Hh * 2;
    short* wg_bf    = (short*)(ws + off);               off += 131072;
    short* wp_bf    = (short*)(ws + off);               off += 131072;
    float* qbias_g  = (float*)(ws + off);               off += 131072;
    float* qbias_p  = (float*)(ws + off);               off += 131072;
    float* scores_g = (float*)(ws + off);               off += 524288;
    float* att      = (float*)(ws + off);               off += 524288;
    float* gpart    = (float*)(ws + off);               // 1 MB

    prep_kernel<<<384, 256, 0, stream>>>(wg, wp, query, wqg, bg, wg_bf, wp_bf, qbias_g);
    // glimpse scores: fp32 ref in, bf16 side-output; unmasked (softmax applies mask)
    scores_mfma<0, 1><<<2048, 256, 0, stream>>>(
        ref, nullptr, ref_bf, wg_bf, qbias_g, vg, nullptr, scores_g);
    softmax_kernel<<<Bb, Ss, 0, stream>>>(scores_g, mask, att);
    glimpse_part<<<dim3(Bb, 8), 256, 0, stream>>>((const unsigned*)ref_bf, att, gpart);
    qbias_p_kernel<<<Bb, Hh, 0, stream>>>(gpart, query, wqp, bp, qbias_p);
    // pointer scores: bf16 ref in, masked, straight to d_out
    scores_mfma<1, 0><<<2048, 256, 0, stream>>>(
        nullptr, ref_bf, nullptr, wp_bf, qbias_p, vp, mask, out);
}

// Round 9
// 311.131 us; speedup vs baseline: 1.5598x; 1.5598x over previous
//
#include <hip/hip_runtime.h>

// B=128, S=1024, H=256
#define Bb 128
#define Ss 1024
#define Hh 256
#define NEGF 1e9f

typedef short bf16x8 __attribute__((ext_vector_type(8)));
typedef float f32x4 __attribute__((ext_vector_type(4)));

__device__ __forceinline__ short f2bf(float f) {
    union { float f; unsigned u; } c; c.f = f;
    return (short)((c.u + 0x8000u) >> 16);
}

__device__ __forceinline__ float bfhi2f(unsigned u) {
    union { unsigned u; float f; } c; c.u = u & 0xFFFF0000u; return c.f;
}
__device__ __forceinline__ float bflo2f(unsigned u) {
    union { unsigned u; float f; } c; c.u = u << 16; return c.f;
}

// packed fp32->bf16 (RNE), 1 instr per 2 elements
__device__ __forceinline__ unsigned cvt_pk_bf16(float a, float b) {
    unsigned r;
    asm("v_cvt_pk_bf16_f32 %0, %1, %2" : "=v"(r) : "v"(a), "v"(b));
    return r;
}

__device__ __forceinline__ float fast_tanh(float x) {
    float cl = fminf(fmaxf(x, -10.f), 10.f);
    float e = __expf(2.f * cl);
    return (e - 1.f) * __builtin_amdgcn_rcpf(e + 1.f);
}

// async global->LDS, 16B per lane; dest = (wave-uniform) lds base + lane*16
__device__ __forceinline__ void stage16(const void* g, short* l) {
    __builtin_amdgcn_global_load_lds((const __attribute__((address_space(1))) void*)g,
                                     (__attribute__((address_space(3))) void*)l, 16, 0, 0);
}

// counted vmcnt wait: vm[3:0] | exp[6:4]=7 | lgkm[11:8]=15 (exp,lgkm = no-wait)
#define WAITVM(N) { __builtin_amdgcn_s_waitcnt(0x0F70 | (N)); __builtin_amdgcn_sched_barrier(0); }

// ---------------- prep:
//  blocks [0,256):      wg,wp fp32 -> bf16
//  blocks [256,384):    qbias_g[b,h] = query[b,:]·wqg[h,:] + bg[h]
//  blocks [384,16768):  ref fp32 -> ref_bf bf16 (streaming, 8 elems/thread, ~BW-bound)
__global__ __launch_bounds__(256) void prep_kernel(const float* __restrict__ wg,
                                                   const float* __restrict__ wp,
                                                   const float* __restrict__ query,
                                                   const float* __restrict__ wqg,
                                                   const float* __restrict__ bg,
                                                   const float* __restrict__ ref,
                                                   short* __restrict__ wgb,
                                                   short* __restrict__ wpb,
                                                   float* __restrict__ qbias_g,
                                                   short* __restrict__ refb) {
    int blk = blockIdx.x, t = threadIdx.x;
    if (blk < 256) {
        int i = blk * 256 + t;
        wgb[i] = f2bf(wg[i]);
        wpb[i] = f2bf(wp[i]);
    } else if (blk < 384) {
        int b = blk - 256;
        const float4* qr = (const float4*)(query + b * Hh);
        const float4* wr = (const float4*)(wqg + t * Hh);
        float acc = 0.f;
#pragma unroll 8
        for (int i = 0; i < Hh / 4; ++i) {
            float4 q4 = qr[i], w4 = wr[i];
            acc += q4.x * w4.x + q4.y * w4.y + q4.z * w4.z + q4.w * w4.w;
        }
        qbias_g[b * Hh + t] = acc + bg[t];
    } else {
        size_t i = (size_t)(blk - 384) * 2048 + (size_t)t * 8;
        const float4* p4 = (const float4*)(ref + i);
        float4 a = p4[0], b4 = p4[1];
        union { unsigned u[4]; bf16x8 v; } cv;
        cv.u[0] = cvt_pk_bf16(a.x, a.y);
        cv.u[1] = cvt_pk_bf16(a.z, a.w);
        cv.u[2] = cvt_pk_bf16(b4.x, b4.y);
        cv.u[3] = cvt_pk_bf16(b4.z, b4.w);
        *(bf16x8*)(refb + i) = cv.v;
    }
}

// ---------------- Fused scores GEMM v9: bf16-only, W-in-regs, 4-buf deep pipeline.
// Grid = 512 blocks x 512 threads (8 waves), 2 blocks/CU (40 KB LDS, VGPR<=128).
// Wave w holds W n-slice [w*32,w*32+32) in regs (bfrag[2][8]=64 VGPR, L2-hot).
// Block owns 256 rows = 16 tiles of 16 rows; tile tt in Abuf[tt&3] (8 KB, fragment
// order [kb-region][lane][16B]; wave w stages region kb=w with ONE global_load_lds).
// Pipeline: prologue stages tiles 0,1,2. Iter tt: WAITVM(2) (own tile-tt stage
// retired; 2 tiles stay in flight = ~2 iters (~900cyc) of latency cover) ->
// s_barrier (all waves' regions of tile tt in LDS; also proves all waves finished
// reading buf[(tt-1)&3]) -> stage(tt+3) into buf[(tt+3)&3]==buf[(tt-1)&3] (WAR-safe
// per the barrier) -> 8 ds_read_b128 + 16 MFMA (two 8-chains) + tanh*v + shfl-reduce
// into wave-exclusive partial slot. No stores, no lgkm protocol, 1 barrier/iter.
// Tail waits: tt=14 -> 1, tt=15 -> 0 (stage only for tt<=12).
template <int MASKED>
__global__ __launch_bounds__(512, 2) void scores_mfma(const short* __restrict__ refb,
                                                      const short* __restrict__ Wbf,
                                                      const float* __restrict__ qbias,
                                                      const float* __restrict__ vvec,
                                                      const int* __restrict__ mask,
                                                      float* __restrict__ out) {
    __shared__ __align__(16) short Abuf[4][4096];  // 4 x 8 KB bf16 tiles
    __shared__ float partial[8][256];              // 8 KB
    const int t = threadIdx.x;
    const int w = t >> 6;
    const int lane = t & 63;
    const int nl = lane & 15;
    const int quad = lane >> 4;
    const int b = blockIdx.x >> 2;
    const int row0 = (blockIdx.x & 3) * 256;

    // persistent W fragments (issued first: oldest vmcnt slots, retired by first WAITVM)
    bf16x8 bfrag[2][8];
#pragma unroll
    for (int nc2 = 0; nc2 < 2; ++nc2) {
        const short* wpr = Wbf + (w * 32 + nc2 * 16 + nl) * Hh + quad * 8;
#pragma unroll
        for (int kb = 0; kb < 8; ++kb)
            bfrag[nc2][kb] = *(const bf16x8*)(wpr + kb * 32);
    }
    const float qb0 = qbias[b * Hh + w * 32 + nl];
    const float qb1 = qbias[b * Hh + w * 32 + 16 + nl];
    const float vv0 = vvec[w * 32 + nl];
    const float vv1 = vvec[w * 32 + 16 + nl];

    // stage tile tt: wave w supplies k-chunk kb=w; lane l -> row nl=l&15,
    // cols w*32+(l>>4)*8; dest linear lane*16B in region [w*512, w*512+512)
    auto stage = [&](int tt) {
        const short* g = refb + ((size_t)b * Ss + row0 + tt * 16 + nl) * Hh + w * 32 + quad * 8;
        stage16(g, &Abuf[tt & 3][w * 512]);
    };

    stage(0);
    stage(1);
    stage(2);

#pragma unroll 1
    for (int tt = 0; tt < 16; ++tt) {
        if (tt <= 13)      WAITVM(2)
        else if (tt == 14) WAITVM(1)
        else               WAITVM(0)
        __builtin_amdgcn_s_barrier();          // all regions of tile tt visible
        __builtin_amdgcn_sched_barrier(0);
        if (tt <= 12) stage(tt + 3);           // refill the buffer freed at this barrier

        const short* bufp = Abuf[tt & 3];
        f32x4 c0 = {0.f, 0.f, 0.f, 0.f};
        f32x4 c1 = {0.f, 0.f, 0.f, 0.f};
#pragma unroll
        for (int kb = 0; kb < 8; ++kb) {
            bf16x8 af = *(const bf16x8*)&bufp[kb * 512 + lane * 8];
            c0 = __builtin_amdgcn_mfma_f32_16x16x32_bf16(af, bfrag[0][kb], c0, 0, 0, 0);
            c1 = __builtin_amdgcn_mfma_f32_16x16x32_bf16(af, bfrag[1][kb], c1, 0, 0, 0);
        }
        // C/D: col = lane&15 (n-lane), row = quad*4 + r ; reduce over 16 n-lanes
#pragma unroll
        for (int r = 0; r < 4; ++r) {
            float s = fast_tanh(c0[r] + qb0) * vv0 + fast_tanh(c1[r] + qb1) * vv1;
            s += __shfl_xor(s, 1, 64);
            s += __shfl_xor(s, 2, 64);
            s += __shfl_xor(s, 4, 64);
            s += __shfl_xor(s, 8, 64);
            if (nl == 0) partial[w][tt * 16 + quad * 4 + r] = s;
        }
    }

    __syncthreads();
    if (t < 256) {
        float s = 0.f;
#pragma unroll
        for (int g = 0; g < 8; ++g) s += partial[g][t];
        if (MASKED) s -= (float)mask[b * Ss + row0 + t] * NEGF;
        out[(size_t)b * Ss + row0 + t] = s;
    }
}

// ---------------- Softmax over S per batch (mask applied) -> att ----------------
__global__ __launch_bounds__(1024) void softmax_kernel(const float* __restrict__ scores,
                                                       const int* __restrict__ mask,
                                                       float* __restrict__ att) {
    int b = blockIdx.x, t = threadIdx.x;
    __shared__ float red[16];
    int idx = b * Ss + t;
    float x = scores[idx] - (float)mask[idx] * NEGF;

    float m = x;
#pragma unroll
    for (int o = 1; o < 64; o <<= 1) m = fmaxf(m, __shfl_xor(m, o, 64));
    if ((t & 63) == 0) red[t >> 6] = m;
    __syncthreads();
    float M = red[0];
#pragma unroll
    for (int j = 1; j < 16; ++j) M = fmaxf(M, red[j]);
    __syncthreads();

    float e = __expf(x - M);
    float s = e;
#pragma unroll
    for (int o = 1; o < 64; o <<= 1) s += __shfl_xor(s, o, 64);
    if ((t & 63) == 0) red[t >> 6] = s;
    __syncthreads();
    float S = 0.f;
#pragma unroll
    for (int j = 0; j < 16; ++j) S += red[j];

    att[idx] = e * __builtin_amdgcn_rcpf(S);
}

// ---------------- Glimpse partial (bf16 ref, L3-hot): gpart[b,q,d] = sum att*ref
__global__ __launch_bounds__(256) void glimpse_part(const unsigned* __restrict__ refb,
                                                    const float* __restrict__ att,
                                                    float* __restrict__ gpart) {
    int b = blockIdx.x, q = blockIdx.y, t = threadIdx.x;
    const int c = t & 31;      // 16B chunk: d = c*8 .. c*8+7
    const int rg = t >> 5;     // row group 0..7
    __shared__ float part[8][Hh];
    const unsigned* base = refb + ((size_t)(b * Ss + q * 128)) * (Hh / 2);
    const float* ap = att + b * Ss + q * 128;

    float acc[8] = {0.f, 0.f, 0.f, 0.f, 0.f, 0.f, 0.f, 0.f};
#pragma unroll 4
    for (int it = 0; it < 16; ++it) {
        int row = it * 8 + rg;
        float a = ap[row];
        uint4 v = *(const uint4*)(base + (size_t)row * (Hh / 2) + c * 4);
        acc[0] += a * bflo2f(v.x); acc[1] += a * bfhi2f(v.x);
        acc[2] += a * bflo2f(v.y); acc[3] += a * bfhi2f(v.y);
        acc[4] += a * bflo2f(v.z); acc[5] += a * bfhi2f(v.z);
        acc[6] += a * bflo2f(v.w); acc[7] += a * bfhi2f(v.w);
    }
#pragma unroll
    for (int j = 0; j < 8; ++j) part[rg][c * 8 + j] = acc[j];
    __syncthreads();
    float s = 0.f;
#pragma unroll
    for (int g = 0; g < 8; ++g) s += part[g][t];
    gpart[(size_t)(b * 8 + q) * Hh + t] = s;
}

// ---------------- qbias_p[b,h] = sum_d glimpse[b,d]*wqp[h,d] + bp[h] ------------
__global__ __launch_bounds__(256) void qbias_p_kernel(const float* __restrict__ gpart,
                                                      const float* __restrict__ query,
                                                      const float* __restrict__ wqp,
                                                      const float* __restrict__ bp,
                                                      float* __restrict__ out) {
    int b = blockIdx.x, t = threadIdx.x;
    __shared__ __align__(16) float gl[Hh];
    float g = query[b * Hh + t];
#pragma unroll
    for (int q = 0; q < 8; ++q) g += gpart[(b * 8 + q) * Hh + t];
    gl[t] = g;
    __syncthreads();
    const float4* wr = (const float4*)(wqp + t * Hh);
    const float4* gp = (const float4*)gl;
    float acc = 0.f;
#pragma unroll 8
    for (int i = 0; i < Hh / 4; ++i) {
        float4 w4 = wr[i];
        float4 g4 = gp[i];
        acc += w4.x * g4.x + w4.y * g4.y + w4.z * g4.z + w4.w * g4.w;
    }
    out[b * Hh + t] = acc + bp[t];
}

extern "C" void kernel_launch(void* const* d_in, const int* in_sizes, int n_in,
                              void* d_out, int out_size, void* d_ws, size_t ws_size,
                              hipStream_t stream) {
    const float* ref   = (const float*)d_in[0];
    const float* query = (const float*)d_in[1];
    const int*   mask  = (const int*)d_in[2];
    const float* wg    = (const float*)d_in[3];
    const float* bg    = (const float*)d_in[4];
    const float* wqg   = (const float*)d_in[5];
    const float* vg    = (const float*)d_in[6];
    const float* wp    = (const float*)d_in[7];
    const float* bp    = (const float*)d_in[8];
    const float* wqp   = (const float*)d_in[9];
    const float* vp    = (const float*)d_in[10];
    float* out = (float*)d_out;

    char* ws = (char*)d_ws;
    short* ref_bf   = (short*)(ws + 0);          // 64 MB (B*S*H bf16)
    size_t off = (size_t)Bb * Ss * Hh * 2;
    short* wg_bf    = (short*)(ws + off);               off += 131072;
    short* wp_bf    = (short*)(ws + off);               off += 131072;
    float* qbias_g  = (float*)(ws + off);               off += 131072;
    float* qbias_p  = (float*)(ws + off);               off += 131072;
    float* scores_g = (float*)(ws + off);               off += 524288;
    float* att      = (float*)(ws + off);               off += 524288;
    float* gpart    = (float*)(ws + off);               // 1 MB

    // prep: weight converts + qbias_g + full ref->bf16 convert (streaming, BW-bound)
    prep_kernel<<<16768, 256, 0, stream>>>(wg, wp, query, wqg, bg, ref,
                                           wg_bf, wp_bf, qbias_g, ref_bf);
    // glimpse scores (unmasked; softmax applies mask)
    scores_mfma<0><<<512, 512, 0, stream>>>(ref_bf, wg_bf, qbias_g, vg, nullptr, scores_g);
    softmax_kernel<<<Bb, Ss, 0, stream>>>(scores_g, mask, att);
    glimpse_part<<<dim3(Bb, 8), 256, 0, stream>>>((const unsigned*)ref_bf, att, gpart);
    qbias_p_kernel<<<Bb, Hh, 0, stream>>>(gpart, query, wqp, bp, qbias_p);
    // pointer scores: masked, straight to d_out
    scores_mfma<1><<<512, 512, 0, stream>>>(ref_bf, wp_bf, qbias_p, vp, mask, out);
}